// Round 6
// baseline (218.869 us; speedup 1.0000x reference)
//
#include <hip/hip_runtime.h>

typedef __bf16 bf16x8 __attribute__((ext_vector_type(8)));
typedef float f32x4 __attribute__((ext_vector_type(4)));
typedef unsigned short ushort8 __attribute__((ext_vector_type(8)));

#define C_DIM 512
#define N_DIM 4096
#define NBATCH 16
#define PSTRIDE ((size_t)NBATCH * C_DIM * C_DIM)   // elements per energy partial

// ---------- helpers ----------

__device__ __forceinline__ unsigned short f2bf(float f) {
  unsigned int u = __builtin_bit_cast(unsigned int, f);
  u += 0x7FFFu + ((u >> 16) & 1u);
  return (unsigned short)(u >> 16);
}

__device__ __forceinline__ void gload_lds16(const void* g, void* l) {
  __builtin_amdgcn_global_load_lds(
      (const __attribute__((address_space(1))) void*)g,
      (__attribute__((address_space(3))) void*)l, 16, 0, 0);
}

// ---------- cast + transpose: x (fp32) -> q (bf16) + qT (bf16) ----------

__global__ __launch_bounds__(256) void cast_transpose(
    const float* __restrict__ x, unsigned short* __restrict__ q,
    unsigned short* __restrict__ qT) {
  int bidx = blockIdx.x;
  int nt = bidx & 63;
  int ct = (bidx >> 6) & 7;
  int b  = bidx >> 9;
  int n0 = nt * 64, c0 = ct * 64;

  const float* xb = x + (size_t)b * C_DIM * N_DIM;
  unsigned short* qb = q + (size_t)b * C_DIM * N_DIM;
  unsigned short* qTb = qT + (size_t)b * N_DIM * C_DIM;

  __shared__ __align__(16) unsigned int Ls[64 * 32];

  int t = threadIdx.x;
  int j = t & 63;
  int i2b = t >> 6;

#pragma unroll
  for (int p = 0; p < 8; ++p) {
    int i2 = p * 4 + i2b;
    int row0 = c0 + 2 * i2;
    float f0 = xb[(size_t)row0 * N_DIM + n0 + j];
    float f1 = xb[(size_t)(row0 + 1) * N_DIM + n0 + j];
    unsigned short b0 = f2bf(f0), b1 = f2bf(f1);
    qb[(size_t)row0 * N_DIM + n0 + j] = b0;
    qb[(size_t)(row0 + 1) * N_DIM + n0 + j] = b1;
    unsigned int val = (unsigned int)b0 | ((unsigned int)b1 << 16);
    Ls[j * 32 + (((i2 >> 2) ^ (j & 7)) * 4) + (i2 & 3)] = val;
  }
  __syncthreads();

  int n = t >> 2;
  int a = t & 3;
  const uint4* Lsv = reinterpret_cast<const uint4*>(Ls);
  uint4 v0 = Lsv[(n * 32 + ((a * 2) ^ (n & 7)) * 4) >> 2];
  uint4 v1 = Lsv[(n * 32 + ((a * 2 + 1) ^ (n & 7)) * 4) >> 2];
  unsigned short* dst = qTb + (size_t)(n0 + n) * C_DIM + c0 + a * 16;
  reinterpret_cast<uint4*>(dst)[0] = v0;
  reinterpret_cast<uint4*>(dst)[1] = v1;
}

// ---------- simple cast (fallback tier) ----------

__global__ __launch_bounds__(256) void cast_kernel(
    const float* __restrict__ x, unsigned short* __restrict__ q, long n8) {
  long stride = (long)gridDim.x * blockDim.x;
  for (long i = (long)blockIdx.x * blockDim.x + threadIdx.x; i < n8; i += stride) {
    const float4* xv = reinterpret_cast<const float4*>(x) + i * 2;
    float4 a = xv[0];
    float4 b = xv[1];
    ushort8 o;
    o[0] = f2bf(a.x); o[1] = f2bf(a.y); o[2] = f2bf(a.z); o[3] = f2bf(a.w);
    o[4] = f2bf(b.x); o[5] = f2bf(b.y); o[6] = f2bf(b.z); o[7] = f2bf(b.w);
    reinterpret_cast<ushort8*>(q)[i] = o;
  }
}

// ---------- energy partials: ep[ks][b] = q[b](ks-slice) @ q[b]^T ----------

__global__ __launch_bounds__(256) void gemm_qqt(
    const unsigned short* __restrict__ q, float* __restrict__ epart, int ksbits) {
  const int K = N_DIM;
  int bidx = blockIdx.x;
  int ks = bidx & ((1 << ksbits) - 1);
  int rest = bidx >> ksbits;
  int p = rest & 15;
  int b = rest >> 4;
  int tr = p >> 2, tc = p & 3;
  const unsigned short* Abase = q + (size_t)(b * C_DIM + tr * 128) * K;
  const unsigned short* Bbase = q + (size_t)(b * C_DIM + tc * 128) * K;
  float* Cp = epart + (size_t)ks * PSTRIDE + (size_t)b * C_DIM * C_DIM;

  __shared__ __align__(16) unsigned short As[128 * 64];
  __shared__ __align__(16) unsigned short Bs[128 * 64];

  int t = threadIdx.x;
  int lane = t & 63;
  int w = t >> 6;
  int wr = w >> 1, wc = w & 1;

  f32x4 acc[4][4] = {};

  int klen = K >> ksbits;
  int k0beg = ks * klen;
  for (int k0 = k0beg; k0 < k0beg + klen; k0 += 64) {
#pragma unroll
    for (int i = 0; i < 4; ++i) {
      int c = i * 256 + t;
      int row = c >> 3, jp = c & 7;
      int scol = ((jp ^ (row & 7)) * 8);
      gload_lds16(Abase + (size_t)row * K + k0 + scol, As + c * 8);
      gload_lds16(Bbase + (size_t)row * K + k0 + scol, Bs + c * 8);
    }
    __syncthreads();
#pragma unroll
    for (int kk = 0; kk < 2; ++kk) {
      bf16x8 af[4], bfr[4];
#pragma unroll
      for (int mi = 0; mi < 4; ++mi) {
        int row = wr * 64 + mi * 16 + (lane & 15);
        int ch = (kk * 4 + (lane >> 4)) ^ (row & 7);
        af[mi] = *reinterpret_cast<const bf16x8*>(As + row * 64 + ch * 8);
      }
#pragma unroll
      for (int ni = 0; ni < 4; ++ni) {
        int row = wc * 64 + ni * 16 + (lane & 15);
        int ch = (kk * 4 + (lane >> 4)) ^ (row & 7);
        bfr[ni] = *reinterpret_cast<const bf16x8*>(Bs + row * 64 + ch * 8);
      }
#pragma unroll
      for (int mi = 0; mi < 4; ++mi)
#pragma unroll
        for (int ni = 0; ni < 4; ++ni)
          acc[mi][ni] = __builtin_amdgcn_mfma_f32_16x16x32_bf16(
              af[mi], bfr[ni], acc[mi][ni], 0, 0, 0);
    }
    __syncthreads();
  }

  int r0 = tr * 128 + wr * 64;
  int c0 = tc * 128 + wc * 64;
#pragma unroll
  for (int mi = 0; mi < 4; ++mi)
#pragma unroll
    for (int ni = 0; ni < 4; ++ni)
#pragma unroll
      for (int r = 0; r < 4; ++r) {
        int row = r0 + mi * 16 + (lane >> 4) * 4 + r;
        int col = c0 + ni * 16 + (lane & 15);
        Cp[(size_t)row * C_DIM + col] = acc[mi][ni][r];
      }
}

// ---------- softmax over sum of partials ----------

__global__ __launch_bounds__(256) void softmax_rows(
    const float* __restrict__ epart, unsigned short* __restrict__ att, int ns) {
  int w = threadIdx.x >> 6;
  int lane = threadIdx.x & 63;
  int row = blockIdx.x * 4 + w;
  const float* e0 = epart + (size_t)row * C_DIM;
  unsigned short* a = att + (size_t)row * C_DIM;
  float v[8];
  float mn = 3.0e38f;
#pragma unroll
  for (int j = 0; j < 8; ++j) {
    float s = e0[j * 64 + lane];
    if (ns == 2) s += e0[PSTRIDE + j * 64 + lane];
    v[j] = s;
    mn = fminf(mn, s);
  }
#pragma unroll
  for (int s = 32; s >= 1; s >>= 1) mn = fminf(mn, __shfl_xor(mn, s));
  float p[8];
  float sum = 0.f;
#pragma unroll
  for (int j = 0; j < 8; ++j) {
    p[j] = __expf(mn - v[j]);
    sum += p[j];
  }
#pragma unroll
  for (int s = 32; s >= 1; s >>= 1) sum += __shfl_xor(sum, s);
  float inv = 1.0f / sum;
#pragma unroll
  for (int j = 0; j < 8; ++j) a[j * 64 + lane] = f2bf(p[j] * inv);
}

// ---------- out = gamma * (att @ q) + x via qT (NT GEMM, 128x256 tile) ----------
// 4 waves, wave-tile 64x128 (acc[4][8]). Grid 1024 = 16 b x 16 tc x 4 tr
// (tr inner: consecutive blocks share the qT B-panel). XCD-swizzled.

__global__ __launch_bounds__(256) void gemm_av(
    const unsigned short* __restrict__ att, const unsigned short* __restrict__ qT,
    const float* __restrict__ x, const float* __restrict__ gamma,
    float* __restrict__ out) {
  // bijective XCD swizzle: 1024 blocks, 8 XCDs, 128 logical per XCD
  int l = (blockIdx.x & 7) * 128 + (blockIdx.x >> 3);
  int tr = l & 3;
  int tc = (l >> 2) & 15;
  int b  = l >> 6;

  const unsigned short* Abase = att + (size_t)(b * C_DIM + tr * 128) * C_DIM;
  const unsigned short* Bbase = qT + (size_t)(b * N_DIM + tc * 256) * C_DIM;

  __shared__ __align__(16) unsigned short As[128 * 64];   // 16 KB
  __shared__ __align__(16) unsigned short Bs[256 * 64];   // 32 KB

  int t = threadIdx.x;
  int lane = t & 63;
  int w = t >> 6;
  int wr = w >> 1, wc = w & 1;   // wave-tile: rows wr*64, cols wc*128

  f32x4 acc[4][8] = {};

  for (int k0 = 0; k0 < C_DIM; k0 += 64) {
    // A tile: 1024 chunks; B tile: 2048 chunks. Swizzled stage.
#pragma unroll
    for (int i = 0; i < 4; ++i) {
      int c = i * 256 + t;
      int row = c >> 3, jp = c & 7;
      int scol = ((jp ^ (row & 7)) * 8);
      gload_lds16(Abase + (size_t)row * C_DIM + k0 + scol, As + c * 8);
    }
#pragma unroll
    for (int i = 0; i < 8; ++i) {
      int c = i * 256 + t;
      int row = c >> 3, jp = c & 7;
      int scol = ((jp ^ (row & 7)) * 8);
      gload_lds16(Bbase + (size_t)row * C_DIM + k0 + scol, Bs + c * 8);
    }
    __syncthreads();
#pragma unroll
    for (int kk = 0; kk < 2; ++kk) {
      bf16x8 af[4], bfr[8];
#pragma unroll
      for (int mi = 0; mi < 4; ++mi) {
        int row = wr * 64 + mi * 16 + (lane & 15);
        int ch = (kk * 4 + (lane >> 4)) ^ (row & 7);
        af[mi] = *reinterpret_cast<const bf16x8*>(As + row * 64 + ch * 8);
      }
#pragma unroll
      for (int ni = 0; ni < 8; ++ni) {
        int row = wc * 128 + ni * 16 + (lane & 15);
        int ch = (kk * 4 + (lane >> 4)) ^ (row & 7);
        bfr[ni] = *reinterpret_cast<const bf16x8*>(Bs + row * 64 + ch * 8);
      }
#pragma unroll
      for (int mi = 0; mi < 4; ++mi)
#pragma unroll
        for (int ni = 0; ni < 8; ++ni)
          acc[mi][ni] = __builtin_amdgcn_mfma_f32_16x16x32_bf16(
              af[mi], bfr[ni], acc[mi][ni], 0, 0, 0);
    }
    __syncthreads();
  }

  float g = gamma[0];
  const float* xb = x + (size_t)b * C_DIM * N_DIM;
  float* ob = out + (size_t)b * C_DIM * N_DIM;
  int colbase = tc * 256 + wc * 128 + (lane & 15);
#pragma unroll
  for (int mi = 0; mi < 4; ++mi) {
#pragma unroll
    for (int r = 0; r < 4; ++r) {
      int row = tr * 128 + wr * 64 + mi * 16 + (lane >> 4) * 4 + r;
      const float* xrow = xb + (size_t)row * N_DIM + colbase;
      float* orow = ob + (size_t)row * N_DIM + colbase;
#pragma unroll
      for (int ni = 0; ni < 8; ++ni)
        orow[ni * 16] = fmaf(g, acc[mi][ni][r], xrow[ni * 16]);
    }
  }
}

// ---------- fallback gemm_av (no qT): reg-transpose B ----------

__global__ __launch_bounds__(256) void gemm_av_fb(
    const unsigned short* __restrict__ att, const unsigned short* __restrict__ q,
    const float* __restrict__ x, const float* __restrict__ gamma,
    float* __restrict__ out) {
  int bidx = blockIdx.x;
  int b  = bidx >> 7;
  int tr = (bidx >> 5) & 3;
  int tc = bidx & 31;

  const unsigned short* Abase = att + (size_t)(b * C_DIM + tr * 128) * C_DIM;
  const unsigned short* qb = q + (size_t)b * C_DIM * N_DIM;

  __shared__ __align__(16) unsigned short As[128 * 64];
  __shared__ __align__(16) unsigned short Bs[128][72];

  int t = threadIdx.x;
  int lane = t & 63;
  int w = t >> 6;
  int wr = w >> 1, wc = w & 1;

  f32x4 acc[4][4] = {};

  for (int k0 = 0; k0 < C_DIM; k0 += 64) {
#pragma unroll
    for (int i = 0; i < 4; ++i) {
      int c = i * 256 + t;
      int row = c >> 3, jp = c & 7;
      int scol = ((jp ^ (row & 7)) * 8);
      gload_lds16(Abase + (size_t)row * C_DIM + k0 + scol, As + c * 8);
    }
#pragma unroll
    for (int i = 0; i < 2; ++i) {
      int u = i * 256 + t;
      int oct = u & 15;
      int dp = u >> 4;
      int d = dp * 2;
      int n = oct * 8;
      const unsigned short* src = qb + (size_t)(k0 + d) * N_DIM + tc * 128 + n;
      ushort8 rA = *reinterpret_cast<const ushort8*>(src);
      ushort8 rB = *reinterpret_cast<const ushort8*>(src + N_DIM);
#pragma unroll
      for (int m = 0; m < 8; ++m) {
        unsigned int val = (unsigned int)rA[m] | ((unsigned int)rB[m] << 16);
        *reinterpret_cast<unsigned int*>(&Bs[n + m][d]) = val;
      }
    }
    __syncthreads();
#pragma unroll
    for (int kk = 0; kk < 2; ++kk) {
      bf16x8 af[4], bfr[4];
#pragma unroll
      for (int mi = 0; mi < 4; ++mi) {
        int row = wr * 64 + mi * 16 + (lane & 15);
        int ch = (kk * 4 + (lane >> 4)) ^ (row & 7);
        af[mi] = *reinterpret_cast<const bf16x8*>(As + row * 64 + ch * 8);
      }
#pragma unroll
      for (int ni = 0; ni < 4; ++ni)
        bfr[ni] = *reinterpret_cast<const bf16x8*>(
            &Bs[wc * 64 + ni * 16 + (lane & 15)][kk * 32 + (lane >> 4) * 8]);
#pragma unroll
      for (int mi = 0; mi < 4; ++mi)
#pragma unroll
        for (int ni = 0; ni < 4; ++ni)
          acc[mi][ni] = __builtin_amdgcn_mfma_f32_16x16x32_bf16(
              af[mi], bfr[ni], acc[mi][ni], 0, 0, 0);
    }
    __syncthreads();
  }

  float g = gamma[0];
  const float* xb = x + (size_t)b * C_DIM * N_DIM;
  float* ob = out + (size_t)b * C_DIM * N_DIM;
  int r0 = tr * 128 + wr * 64;
  int n0 = tc * 128 + wc * 64;
#pragma unroll
  for (int mi = 0; mi < 4; ++mi)
#pragma unroll
    for (int ni = 0; ni < 4; ++ni)
#pragma unroll
      for (int r = 0; r < 4; ++r) {
        int row = r0 + mi * 16 + (lane >> 4) * 4 + r;
        int col = n0 + ni * 16 + (lane & 15);
        size_t idx = (size_t)row * N_DIM + col;
        ob[idx] = fmaf(g, acc[mi][ni][r], xb[idx]);
      }
}

// ---------- launch ----------

extern "C" void kernel_launch(void* const* d_in, const int* in_sizes, int n_in,
                              void* d_out, int out_size, void* d_ws, size_t ws_size,
                              hipStream_t stream) {
  const float* x = (const float*)d_in[0];
  const float* gamma = (const float*)d_in[1];
  float* out = (float*)d_out;
  char* ws = (char*)d_ws;

  const size_t QSZ = 67108864;   // bf16 [16][512][4096]
  const size_t ESZ = 16777216;   // f32  [16][512][512] (one partial)
  const size_t ASZ = 8388608;    // bf16 [16][512][512]
  long n8 = (long)NBATCH * C_DIM * N_DIM / 8;

  if (ws_size >= 2 * QSZ + 2 * ESZ + ASZ) {              // tier A (qT path)
    unsigned short* q  = (unsigned short*)ws;
    unsigned short* qT = (unsigned short*)(ws + QSZ);
    float* ep = (float*)(ws + 2 * QSZ);
    unsigned short* att = (unsigned short*)(ws + 2 * QSZ + 2 * ESZ);
    cast_transpose<<<8192, 256, 0, stream>>>(x, q, qT);
    gemm_qqt<<<512, 256, 0, stream>>>(q, ep, 1);
    softmax_rows<<<2048, 256, 0, stream>>>(ep, att, 2);
    gemm_av<<<1024, 256, 0, stream>>>(att, qT, x, gamma, out);
  } else if (ws_size >= QSZ + 2 * ESZ + ASZ) {           // tier B
    unsigned short* q = (unsigned short*)ws;
    float* ep = (float*)(ws + QSZ);
    unsigned short* att = (unsigned short*)(ws + QSZ + 2 * ESZ);
    cast_kernel<<<2048, 256, 0, stream>>>(x, q, n8);
    gemm_qqt<<<512, 256, 0, stream>>>(q, ep, 1);
    softmax_rows<<<2048, 256, 0, stream>>>(ep, att, 2);
    gemm_av_fb<<<2048, 256, 0, stream>>>(att, q, x, gamma, out);
  } else {                                               // tier C
    unsigned short* q = (unsigned short*)ws;
    float* ep = (float*)(ws + QSZ);
    unsigned short* att = (unsigned short*)(ws + QSZ + ESZ);
    cast_kernel<<<2048, 256, 0, stream>>>(x, q, n8);
    gemm_qqt<<<256, 256, 0, stream>>>(q, ep, 0);
    softmax_rows<<<2048, 256, 0, stream>>>(ep, att, 1);
    gemm_av_fb<<<2048, 256, 0, stream>>>(att, q, x, gamma, out);
  }
}